// Round 3
// baseline (2040.444 us; speedup 1.0000x reference)
//
#include <hip/hip_runtime.h>

#define K_CODES 8192
#define C_DIM   256
#define N_TOTAL 16384      // 16 * 32 * 32
#define HWSZ    1024

// ---- output layout (floats) ----
#define O_ZQ   0
#define O_LOSS 4194304
#define O_IDX  4194305
#define O_PERP 4210689
#define O_W    4210690
#define O_CS   6307842
#define O_EA   6316034

// ---- workspace layout (float offsets) ---- (total ~148 KB; esum lives in out[O_EA])
#define WS_WN    0          // 8192
#define WS_IDX   8192       // 16384 ints
#define WS_CNT   24576      // 8192
#define WS_LPART 32768      // 4096
#define WS_NTOT  36864      // 1

__device__ __forceinline__ bool lexless(float d, int k, float v, int i) {
    return d < v || (d == v && k < i);
}

// ===================== K1: |w_k|^2 (selection metric only) =====================
__global__ __launch_bounds__(256) void k_wnorm(const float* __restrict__ w,
                                               float* __restrict__ wn)
{
    int row  = blockIdx.x * 4 + (threadIdx.x >> 6);
    int lane = threadIdx.x & 63;
    float4 v = *(const float4*)(w + (size_t)row * C_DIM + lane * 4);
    float s = v.x * v.x + v.y * v.y + v.z * v.z + v.w * v.w;
#pragma unroll
    for (int d = 1; d < 64; d <<= 1) s += __shfl_xor(s, d, 64);
    if (lane == 0) wn[row] = s;
}

// ===================== K2: argmin distances =====================
// f32 tile loop selects top-2 candidates; epilogue re-ranks them in the
// REFERENCE's quantized f32 arithmetic: d = fl(fl(a_n + b_k) - fl(2*s_k)),
// a_n = numpy-pairwise(AVX512 order) f32 sum of z^2; s,b from f64; tie -> low idx.
#define MT 32
#define NT 128
#define CK 32

__global__ __launch_bounds__(256) void k_argmin(const float* __restrict__ z,
                                                const float* __restrict__ w,
                                                const float* __restrict__ wn,
                                                int* __restrict__ idx)
{
#pragma clang fp contract(off)
    __shared__ float zs[MT * C_DIM];   // col XOR-swizzled by ((r>>1)&3)<<2
    __shared__ float wt[NT * CK];      // col XOR-swizzled by ((code>>3)&7)<<2

    const int tid = threadIdx.x;
    const int tx  = tid & 15;
    const int ty  = tid >> 4;
    const int m0  = blockIdx.x * MT;
    const int b   = m0 >> 10;
    const int hw0 = m0 & 1023;

    // stage z rows once: coalesced along hw, scatter rows into LDS
    {
        const int i4  = (tid & 7) << 2;
        const int c0s = tid >> 3;
        const float* zp = z + (size_t)b * (C_DIM * HWSZ) + hw0 + i4;
        for (int c = c0s; c < C_DIM; c += 32) {
            float4 v = *(const float4*)(zp + (size_t)c * HWSZ);
            float vv[4] = {v.x, v.y, v.z, v.w};
#pragma unroll
            for (int j = 0; j < 4; ++j) {
                int r = i4 + j;
                zs[r * C_DIM + (c ^ (((r >> 1) & 3) << 2))] = vv[j];
            }
        }
    }
    __syncthreads();

    const int r0  = ty * 2;
    const int zsw = (ty & 3) << 2;

    float v1[2] = {3.4e38f, 3.4e38f}, v2[2] = {3.4e38f, 3.4e38f};
    int   i1[2] = {0, 0},             i2[2] = {0, 0};

    for (int k0 = 0; k0 < K_CODES; k0 += NT) {
        float acc[2][8];
#pragma unroll
        for (int j = 0; j < 2; ++j)
#pragma unroll
            for (int q = 0; q < 8; ++q) acc[j][q] = 0.f;

        for (int c0 = 0; c0 < C_DIM; c0 += CK) {
            __syncthreads();
            {
                const int col = (tid & 7) << 2;
                const int kb  = tid >> 3;
#pragma unroll
                for (int p = 0; p < 4; ++p) {
                    int code = kb + p * 32;
                    float4 v = *(const float4*)(w + (size_t)(k0 + code) * C_DIM + c0 + col);
                    *(float4*)&wt[code * CK + (col ^ (((code >> 3) & 7) << 2))] = v;
                }
            }
            __syncthreads();
#pragma unroll
            for (int c4 = 0; c4 < CK; c4 += 4) {
                float4 za = *(const float4*)&zs[(r0    ) * C_DIM + ((c0 + c4) ^ zsw)];
                float4 zb = *(const float4*)&zs[(r0 + 1) * C_DIM + ((c0 + c4) ^ zsw)];
#pragma unroll
                for (int q = 0; q < 8; ++q) {
                    const int kl = tx * 8 + q;
                    float4 wv = *(const float4*)&wt[kl * CK + (c4 ^ (((kl >> 3) & 7) << 2))];
                    acc[0][q] = fmaf(za.x, wv.x, acc[0][q]);
                    acc[0][q] = fmaf(za.y, wv.y, acc[0][q]);
                    acc[0][q] = fmaf(za.z, wv.z, acc[0][q]);
                    acc[0][q] = fmaf(za.w, wv.w, acc[0][q]);
                    acc[1][q] = fmaf(zb.x, wv.x, acc[1][q]);
                    acc[1][q] = fmaf(zb.y, wv.y, acc[1][q]);
                    acc[1][q] = fmaf(zb.z, wv.z, acc[1][q]);
                    acc[1][q] = fmaf(zb.w, wv.w, acc[1][q]);
                }
            }
        }
#pragma unroll
        for (int q = 0; q < 8; ++q) {
            const int k = k0 + tx * 8 + q;
            const float wnk = wn[k];
#pragma unroll
            for (int j = 0; j < 2; ++j) {
                float d = fmaf(-2.f, acc[j][q], wnk);
                if (lexless(d, k, v1[j], i1[j])) {
                    v2[j] = v1[j]; i2[j] = i1[j]; v1[j] = d; i1[j] = k;
                } else if (lexless(d, k, v2[j], i2[j])) {
                    v2[j] = d; i2[j] = k;
                }
            }
        }
    }

#pragma unroll
    for (int j = 0; j < 2; ++j) {
        // ---- cross-tx butterfly top-2 merge with index-dedup ----
        float a1 = v1[j]; int ai1 = i1[j];
        float a2 = v2[j]; int ai2 = i2[j];
        for (int s = 1; s <= 8; s <<= 1) {
            float b1 = __shfl_xor(a1, s, 64); int bi1 = __shfl_xor(ai1, s, 64);
            float b2 = __shfl_xor(a2, s, 64); int bi2 = __shfl_xor(ai2, s, 64);
            float cv[4] = {a1, a2, b1, b2};
            int   ci[4] = {ai1, ai2, bi1, bi2};
            float f1 = cv[0]; int fi = ci[0];
#pragma unroll
            for (int t = 1; t < 4; ++t)
                if (lexless(cv[t], ci[t], f1, fi)) { f1 = cv[t]; fi = ci[t]; }
            float g1 = 3.4e38f; int gi = 0x7fffffff;
#pragma unroll
            for (int t = 0; t < 4; ++t)
                if (ci[t] != fi && lexless(cv[t], ci[t], g1, gi)) { g1 = cv[t]; gi = ci[t]; }
            a1 = f1; ai1 = fi; a2 = g1; ai2 = gi;
        }

        const int r = r0 + j;

        // ---- f64 dots for the two candidates (16 cols per lane) ----
        const float* wp1 = w + (size_t)ai1 * C_DIM;
        const float* wp2 = w + (size_t)ai2 * C_DIM;
        double s1 = 0, q1 = 0, s2 = 0, q2 = 0;
        const int cb = tx * 16;
#pragma unroll
        for (int cc = 0; cc < 16; cc += 4) {
            const int c = cb + cc;
            float4 zv = *(const float4*)&zs[r * C_DIM + (c ^ zsw)];
            float4 wa = *(const float4*)(wp1 + c);
            float4 wb = *(const float4*)(wp2 + c);
            s1 += (double)zv.x * wa.x + (double)zv.y * wa.y + (double)zv.z * wa.z + (double)zv.w * wa.w;
            q1 += (double)wa.x * wa.x + (double)wa.y * wa.y + (double)wa.z * wa.z + (double)wa.w * wa.w;
            s2 += (double)zv.x * wb.x + (double)zv.y * wb.y + (double)zv.z * wb.z + (double)zv.w * wb.w;
            q2 += (double)wb.x * wb.x + (double)wb.y * wb.y + (double)wb.z * wb.z + (double)wb.w * wb.w;
        }
#pragma unroll
        for (int s = 1; s <= 8; s <<= 1) {
            s1 += __shfl_xor(s1, s, 64);
            q1 += __shfl_xor(q1, s, 64);
            s2 += __shfl_xor(s2, s, 64);
            q2 += __shfl_xor(q2, s, 64);
        }

        // ---- a_n: numpy pairwise f32 sum of z^2, AVX512 NPYV order ----
        // blocks of 128: lanewise ((V0+V1)+(V2+V3))+((V4+V5)+(V6+V7)) over 16 lanes,
        // then _mm512_reduce_add_ps halving tree; a = blk0 + blk1.
        float blk[2];
#pragma unroll
        for (int bb = 0; bb < 2; ++bb) {
            float t[8];
#pragma unroll
            for (int t8 = 0; t8 < 8; ++t8) {
                float zz = zs[r * C_DIM + ((bb * 128 + t8 * 16 + tx) ^ zsw)];
                t[t8] = zz * zz;
            }
            float p01 = t[0] + t[1];
            float p23 = t[2] + t[3];
            float p45 = t[4] + t[5];
            float p67 = t[6] + t[7];
            float W = (p01 + p23) + (p45 + p67);
            W += __shfl_xor(W, 8, 64);   // A_i = W_i + W_{i+8}
            W += __shfl_xor(W, 4, 64);   // B_i = A_i + A_{i+4}
            W += __shfl_xor(W, 2, 64);   // C_i = B_i + B_{i+2}
            W += __shfl_xor(W, 1, 64);   // C_0 + C_1
            blk[bb] = W;
        }
        float af = blk[0] + blk[1];

        // ---- reference-quantized distances; tie -> lowest index ----
        float bf1 = (float)q1;
        float bf2 = (float)q2;
        float sf1 = (float)(2.0 * s1);
        float sf2 = (float)(2.0 * s2);
        float t1a = af + bf1;
        float t1b = af + bf2;
        float d1 = t1a - sf1;
        float d2 = t1b - sf2;
        int best = (d2 < d1 || (d2 == d1 && ai2 < ai1)) ? ai2 : ai1;
        if (tx == 0) idx[m0 + r] = best;
    }
}

// ===================== K3: gather/STE + loss + embed_sum + counts + idx_out =====
__global__ __launch_bounds__(256) void k_gather(const float* __restrict__ z,
                                                const float* __restrict__ w,
                                                const int* __restrict__ idx,
                                                float* __restrict__ zq,
                                                float* __restrict__ oidx,
                                                float* __restrict__ esum,
                                                float* __restrict__ cnt,
                                                float* __restrict__ lpart)
{
    const int bid = blockIdx.x;
    const int b   = bid >> 8;
    const int c   = bid & 255;
    const int tid = threadIdx.x;
    const int hw4 = tid * 4;
    const size_t zoff = (size_t)b * (C_DIM * HWSZ) + (size_t)c * HWSZ + hw4;

    float4 zv = *(const float4*)(z + zoff);
    const int nb = b * HWSZ + hw4;
    int4 iv = *(const int4*)(idx + nb);

    float4 wq;
    wq.x = w[(size_t)iv.x * C_DIM + c];
    wq.y = w[(size_t)iv.y * C_DIM + c];
    wq.z = w[(size_t)iv.z * C_DIM + c];
    wq.w = w[(size_t)iv.w * C_DIM + c];
    *(float4*)(zq + zoff) = wq;

    float dx = wq.x - zv.x, dy = wq.y - zv.y, dz = wq.z - zv.z, dw = wq.w - zv.w;
    float ls = dx * dx + dy * dy + dz * dz + dw * dw;

    atomicAdd(esum + (size_t)iv.x * C_DIM + c, zv.x);
    atomicAdd(esum + (size_t)iv.y * C_DIM + c, zv.y);
    atomicAdd(esum + (size_t)iv.z * C_DIM + c, zv.z);
    atomicAdd(esum + (size_t)iv.w * C_DIM + c, zv.w);

    if (c == 0) {   // idx as floats; odd offset -> scalar stores
        oidx[nb + 0] = (float)iv.x;
        oidx[nb + 1] = (float)iv.y;
        oidx[nb + 2] = (float)iv.z;
        oidx[nb + 3] = (float)iv.w;
    }
    if (c == 1) {
        atomicAdd(cnt + iv.x, 1.f); atomicAdd(cnt + iv.y, 1.f);
        atomicAdd(cnt + iv.z, 1.f); atomicAdd(cnt + iv.w, 1.f);
    }

#pragma unroll
    for (int d = 1; d < 64; d <<= 1) ls += __shfl_xor(ls, d, 64);
    __shared__ float red[4];
    if ((tid & 63) == 0) red[tid >> 6] = ls;
    __syncthreads();
    if (tid == 0) lpart[bid] = red[0] + red[1] + red[2] + red[3];
}

// ===================== K4a: n_total, perplexity, loss =====================
__global__ __launch_bounds__(256) void k_stats(const float* __restrict__ cnt,
                                               const float* __restrict__ cs,
                                               const float* __restrict__ lpart,
                                               float* __restrict__ ntot,
                                               float* __restrict__ out_loss,
                                               float* __restrict__ out_perp)
{
    const int tid = threadIdx.x;
    float sn = 0.f, se = 0.f, sl = 0.f;
    for (int k = tid; k < K_CODES; k += 256) {
        float cn = cnt[k];
        sn += 0.99f * cs[k] + 0.01f * cn;
        float p = cn * (1.f / (float)N_TOTAL);
        se += p * logf(p + 1e-10f);
    }
    for (int i = tid; i < 4096; i += 256) sl += lpart[i];
#pragma unroll
    for (int d = 1; d < 64; d <<= 1) {
        sn += __shfl_xor(sn, d, 64);
        se += __shfl_xor(se, d, 64);
        sl += __shfl_xor(sl, d, 64);
    }
    __shared__ float r[12];
    if ((tid & 63) == 0) { int wv = tid >> 6; r[wv] = sn; r[4 + wv] = se; r[8 + wv] = sl; }
    __syncthreads();
    if (tid == 0) {
        float n = r[0] + r[1] + r[2] + r[3];
        float e = r[4] + r[5] + r[6] + r[7];
        float l = r[8] + r[9] + r[10] + r[11];
        *ntot = n;
        *out_loss = 0.25f * l * (1.f / 4194304.f);
        *out_perp = expf(-e);
    }
}

// ===================== K4b: EMA update + normalized weight =====================
// esum aliases o_ea (scratch-in-output); per-element read-then-overwrite is safe.
__global__ __launch_bounds__(256) void k_update(const float* __restrict__ cs,
                                                const float* __restrict__ cnt,
                                                const float* __restrict__ ea,
                                                const float* __restrict__ esum,
                                                const float* __restrict__ ntot,
                                                float* __restrict__ o_w,
                                                float* __restrict__ o_cs,
                                                float* __restrict__ o_ea)
{
    const int k = blockIdx.x;
    const int c = threadIdx.x;
    float ncs = 0.99f * cs[k] + 0.01f * cnt[k];
    float n = *ntot;
    float sm = (ncs + 1e-5f) / (n + (float)K_CODES * 1e-5f) * n;
    if (c == 0) o_cs[k] = ncs;
    size_t o = (size_t)k * C_DIM + c;
    float v = 0.99f * ea[o] + 0.01f * esum[o];
    o_ea[o] = v;
    o_w[o]  = v / sm;
}

// ===================== launch =====================
extern "C" void kernel_launch(void* const* d_in, const int* in_sizes, int n_in,
                              void* d_out, int out_size, void* d_ws, size_t ws_size,
                              hipStream_t stream)
{
    const float* z  = (const float*)d_in[0];
    const float* w  = (const float*)d_in[1];
    const float* cs = (const float*)d_in[2];
    const float* ea = (const float*)d_in[3];
    float* out = (float*)d_out;
    float* ws  = (float*)d_ws;

    float* wn    = ws + WS_WN;
    int*   idx   = (int*)(ws + WS_IDX);
    float* cnt   = ws + WS_CNT;
    float* lpart = ws + WS_LPART;
    float* ntot  = ws + WS_NTOT;
    float* esum  = out + O_EA;   // scratch-in-output: zeroed, accumulated, overwritten

    hipMemsetAsync(cnt, 0, K_CODES * sizeof(float), stream);
    hipMemsetAsync(esum, 0, (size_t)K_CODES * C_DIM * sizeof(float), stream);

    k_wnorm <<<K_CODES / 4, 256, 0, stream>>>(w, wn);
    k_argmin<<<N_TOTAL / MT, 256, 0, stream>>>(z, w, wn, idx);
    k_gather<<<16 * 256, 256, 0, stream>>>(z, w, idx, out + O_ZQ, out + O_IDX,
                                           esum, cnt, lpart);
    k_stats <<<1, 256, 0, stream>>>(cnt, cs, lpart, ntot, out + O_LOSS, out + O_PERP);
    k_update<<<K_CODES, 256, 0, stream>>>(cs, cnt, ea, esum, ntot,
                                          out + O_W, out + O_CS, out + O_EA);
}

// Round 4
// 652.749 us; speedup vs baseline: 3.1259x; 3.1259x over previous
//
#include <hip/hip_runtime.h>

typedef _Float16 f16;
typedef _Float16 f16x8 __attribute__((ext_vector_type(8)));
typedef float f32x4 __attribute__((ext_vector_type(4)));

#define K_CODES 8192
#define C_DIM   256
#define N_TOTAL 16384      // 16 * 32 * 32
#define HWSZ    1024

// ---- output layout (floats) ----
#define O_ZQ   0
#define O_LOSS 4194304
#define O_IDX  4194305
#define O_PERP 4210689
#define O_W    4210690
#define O_CS   6307842
#define O_EA   6316034

// ---- workspace layout (float offsets) ----
#define WS_WN    0          // 8192
#define WS_IDX   8192       // 16384 ints
#define WS_CNT   24576      // 8192
#define WS_LPART 32768      // 4096
#define WS_NTOT  36864      // 1
#define WS_CAND  40960      // 16384*8 ints

__device__ __forceinline__ bool lexless(float d, int k, float v, int i) {
    return d < v || (d == v && k < i);
}

// ===================== prep: z -> f16 hi/lo, transposed to [row][c] ==========
__global__ __launch_bounds__(256) void k_prepz(const float* __restrict__ z,
                                               f16* __restrict__ zhi,
                                               f16* __restrict__ zlo)
{
    __shared__ float zs[32 * C_DIM];   // col XOR-swizzled by ((r>>1)&3)<<2
    const int tid = threadIdx.x;
    const int m0  = blockIdx.x * 32;
    const int b   = m0 >> 10;
    const int hw0 = m0 & 1023;
    {
        const int i4  = (tid & 7) << 2;
        const int c0s = tid >> 3;
        const float* zp = z + (size_t)b * (C_DIM * HWSZ) + hw0 + i4;
        for (int c = c0s; c < C_DIM; c += 32) {
            float4 v = *(const float4*)(zp + (size_t)c * HWSZ);
            float vv[4] = {v.x, v.y, v.z, v.w};
#pragma unroll
            for (int j = 0; j < 4; ++j) {
                int r = i4 + j;
                zs[r * C_DIM + (c ^ (((r >> 1) & 3) << 2))] = vv[j];
            }
        }
    }
    __syncthreads();
    const int r   = tid >> 3;
    const int cc0 = (tid & 7) * 32;
    const int rsw = ((r >> 1) & 3) << 2;
    const size_t obase = (size_t)(m0 + r) * C_DIM + cc0;
#pragma unroll
    for (int p = 0; p < 4; ++p) {
        f16x8 h, l;
#pragma unroll
        for (int e = 0; e < 8; ++e) {
            float v = zs[r * C_DIM + ((cc0 + p * 8 + e) ^ rsw)];
            f16 hh = (f16)v;
            h[e] = hh;
            l[e] = (f16)(v - (float)hh);
        }
        *(f16x8*)(zhi + obase + p * 8) = h;
        *(f16x8*)(zlo + obase + p * 8) = l;
    }
}

// ===================== prep: w -> f16 hi/lo (elementwise) =====================
__global__ __launch_bounds__(256) void k_prepw(const float* __restrict__ w,
                                               f16* __restrict__ whi,
                                               f16* __restrict__ wlo)
{
    const size_t i8 = ((size_t)blockIdx.x * 256 + threadIdx.x) * 8;
    float4 a = *(const float4*)(w + i8);
    float4 b = *(const float4*)(w + i8 + 4);
    float vv[8] = {a.x, a.y, a.z, a.w, b.x, b.y, b.z, b.w};
    f16x8 h, l;
#pragma unroll
    for (int e = 0; e < 8; ++e) {
        f16 hh = (f16)vv[e];
        h[e] = hh;
        l[e] = (f16)(vv[e] - (float)hh);
    }
    *(f16x8*)(whi + i8) = h;
    *(f16x8*)(wlo + i8) = l;
}

// ===================== K1: |w_k|^2 (selection metric only) =====================
__global__ __launch_bounds__(256) void k_wnorm(const float* __restrict__ w,
                                               float* __restrict__ wn)
{
    int row  = blockIdx.x * 4 + (threadIdx.x >> 6);
    int lane = threadIdx.x & 63;
    float4 v = *(const float4*)(w + (size_t)row * C_DIM + lane * 4);
    float s = v.x * v.x + v.y * v.y + v.z * v.z + v.w * v.w;
#pragma unroll
    for (int d = 1; d < 64; d <<= 1) s += __shfl_xor(s, d, 64);
    if (lane == 0) wn[row] = s;
}

// ===================== K2: MFMA top-2 selection =====================
// 512 thr / 8 waves; wave = 32 rows (2 Mfrags), block = 256 rows x 2048-code
// quarter. w hi/lo tiles (32 codes x 256 k) double-buffered in LDS with
// T2 XOR swizzle; z hi/lo frags resident in VGPRs. 3 MFMA products/frag.
__global__ __launch_bounds__(512, 2) void k_select(
    const f16* __restrict__ zhi, const f16* __restrict__ zlo,
    const f16* __restrict__ whi, const f16* __restrict__ wlo,
    const float* __restrict__ wn, int* __restrict__ cand)
{
    __shared__ f16 wls[2][2][32 * C_DIM];   // [buf][hi/lo][code*256 + swz k]

    const int tid  = threadIdx.x;
    const int wave = tid >> 6;
    const int lane = tid & 63;
    const int l15  = lane & 15;
    const int l4   = lane >> 4;

    const int rowbase = blockIdx.x * 256 + wave * 32;
    const int q       = blockIdx.y;
    const int code0   = q * 2048;

    // ---- A prologue: z frags resident in regs ----
    f16x8 ah[2][8], al[2][8];
#pragma unroll
    for (int mf = 0; mf < 2; ++mf) {
        const f16* zbh = zhi + (size_t)(rowbase + mf * 16 + l15) * C_DIM + l4 * 8;
        const f16* zbl = zlo + (size_t)(rowbase + mf * 16 + l15) * C_DIM + l4 * 8;
#pragma unroll
        for (int ks = 0; ks < 8; ++ks) {
            ah[mf][ks] = *(const f16x8*)(zbh + ks * 32);
            al[mf][ks] = *(const f16x8*)(zbl + ks * 32);
        }
    }

    // ---- staging assignment: hl = tid>>8, code-in-tile, k-chunk ----
    const int s_hl   = tid >> 8;
    const int s_code = (tid >> 3) & 31;
    const int s_ch   = tid & 7;
    const f16* s_src = s_hl ? wlo : whi;
    int s_lds[4];
#pragma unroll
    for (int p = 0; p < 4; ++p) {
        int kk = (s_ch + p * 8) * 8;
        s_lds[p] = s_code * C_DIM + (kk ^ ((s_code & 7) << 3));
    }

    // ---- B-read swizzle bases ----
    const int bsw  = (l15 & 7) << 3;
    const int b_k0 = l4 * 8;

    // ---- top-2 state: 8 row-slots (mf*4 + r) ----
    float v1[8], v2[8]; int i1[8], i2[8];
#pragma unroll
    for (int s = 0; s < 8; ++s) { v1[s] = 3.4e38f; v2[s] = 3.4e38f; i1[s] = 0; i2[s] = 0; }

    // ---- stage tile 0 ----
    {
        const f16* g = s_src + (size_t)(code0 + s_code) * C_DIM + s_ch * 8;
        f16x8 sr[4];
#pragma unroll
        for (int p = 0; p < 4; ++p) sr[p] = *(const f16x8*)(g + p * 64);
#pragma unroll
        for (int p = 0; p < 4; ++p) *(f16x8*)&wls[0][s_hl][s_lds[p]] = sr[p];
    }

    for (int t = 0; t < 64; ++t) {
        __syncthreads();
        const int buf = t & 1;
        const bool more = (t + 1) < 64;
        f16x8 nr[4];
        if (more) {   // issue next-tile global loads early (hide under MFMA)
            const f16* g = s_src + (size_t)(code0 + (t + 1) * 32 + s_code) * C_DIM + s_ch * 8;
#pragma unroll
            for (int p = 0; p < 4; ++p) nr[p] = *(const f16x8*)(g + p * 64);
        }

        f32x4 acc[2][2];
#pragma unroll
        for (int mf = 0; mf < 2; ++mf)
#pragma unroll
            for (int nf = 0; nf < 2; ++nf) acc[mf][nf] = (f32x4){0.f, 0.f, 0.f, 0.f};

#pragma unroll
        for (int ks = 0; ks < 8; ++ks) {
#pragma unroll
            for (int nf = 0; nf < 2; ++nf) {
                const int e = (nf * 16 + l15) * C_DIM + ((ks * 32 + b_k0) ^ bsw);
                f16x8 bh = *(const f16x8*)&wls[buf][0][e];
                f16x8 bl = *(const f16x8*)&wls[buf][1][e];
#pragma unroll
                for (int mf = 0; mf < 2; ++mf) {
                    acc[mf][nf] = __builtin_amdgcn_mfma_f32_16x16x32_f16(ah[mf][ks], bh, acc[mf][nf], 0, 0, 0);
                    acc[mf][nf] = __builtin_amdgcn_mfma_f32_16x16x32_f16(al[mf][ks], bh, acc[mf][nf], 0, 0, 0);
                    acc[mf][nf] = __builtin_amdgcn_mfma_f32_16x16x32_f16(ah[mf][ks], bl, acc[mf][nf], 0, 0, 0);
                }
            }
        }

        // ---- top-2 update (d = |w|^2 - 2 z.w) ----
#pragma unroll
        for (int nf = 0; nf < 2; ++nf) {
            const int code = code0 + t * 32 + nf * 16 + l15;
            const float wnv = wn[code];
#pragma unroll
            for (int mf = 0; mf < 2; ++mf)
#pragma unroll
                for (int r = 0; r < 4; ++r) {
                    const float d = fmaf(-2.f, acc[mf][nf][r], wnv);
                    const int s = mf * 4 + r;
                    if (lexless(d, code, v1[s], i1[s])) {
                        v2[s] = v1[s]; i2[s] = i1[s]; v1[s] = d; i1[s] = code;
                    } else if (lexless(d, code, v2[s], i2[s])) {
                        v2[s] = d; i2[s] = code;
                    }
                }
        }

        if (more) {
#pragma unroll
            for (int p = 0; p < 4; ++p) *(f16x8*)&wls[buf ^ 1][s_hl][s_lds[p]] = nr[p];
        }
    }

    // ---- cross-lane top-2 merge (16-lane groups, index-dedup) + write ----
#pragma unroll
    for (int s = 0; s < 8; ++s) {
        float a1 = v1[s]; int ai1 = i1[s];
        float a2 = v2[s]; int ai2 = i2[s];
        for (int st = 1; st <= 8; st <<= 1) {
            float b1 = __shfl_xor(a1, st, 64); int bi1 = __shfl_xor(ai1, st, 64);
            float b2 = __shfl_xor(a2, st, 64); int bi2 = __shfl_xor(ai2, st, 64);
            float cv[4] = {a1, a2, b1, b2};
            int   ci[4] = {ai1, ai2, bi1, bi2};
            float f1 = cv[0]; int fi = ci[0];
#pragma unroll
            for (int u = 1; u < 4; ++u)
                if (lexless(cv[u], ci[u], f1, fi)) { f1 = cv[u]; fi = ci[u]; }
            float g1 = 3.4e38f; int gi = 0x7fffffff;
#pragma unroll
            for (int u = 0; u < 4; ++u)
                if (ci[u] != fi && lexless(cv[u], ci[u], g1, gi)) { g1 = cv[u]; gi = ci[u]; }
            a1 = f1; ai1 = fi; a2 = g1; ai2 = gi;
        }
        if (l15 == 0) {
            const int row = rowbase + (s >> 2) * 16 + l4 * 4 + (s & 3);
            cand[row * 8 + q * 2 + 0] = ai1;
            cand[row * 8 + q * 2 + 1] = ai2;
        }
    }
}

// ===================== K2b: exact rerank of 8 candidates =====================
// Reproduces np's quantized f32 distance: d = fl(fl(a_n + b_k) - fl(2*s_k)),
// a_n = numpy-pairwise(AVX512 order) f32 sum of z^2; s,b from f64; tie->low idx.
__global__ __launch_bounds__(256) void k_rerank(const float* __restrict__ z,
                                                const float* __restrict__ w,
                                                const int* __restrict__ cand,
                                                int* __restrict__ idx)
{
#pragma clang fp contract(off)
    __shared__ float zs[32 * C_DIM];
    const int tid = threadIdx.x;
    const int m0  = blockIdx.x * 32;
    const int b   = m0 >> 10;
    const int hw0 = m0 & 1023;
    {
        const int i4  = (tid & 7) << 2;
        const int c0s = tid >> 3;
        const float* zp = z + (size_t)b * (C_DIM * HWSZ) + hw0 + i4;
        for (int c = c0s; c < C_DIM; c += 32) {
            float4 v = *(const float4*)(zp + (size_t)c * HWSZ);
            float vv[4] = {v.x, v.y, v.z, v.w};
#pragma unroll
            for (int j = 0; j < 4; ++j) {
                int r = i4 + j;
                zs[r * C_DIM + (c ^ (((r >> 1) & 3) << 2))] = vv[j];
            }
        }
    }
    __syncthreads();

    const int tx  = tid & 15;
    const int ty  = tid >> 4;
    const int zsw = (ty & 3) << 2;

#pragma unroll
    for (int j = 0; j < 2; ++j) {
        const int r   = ty * 2 + j;
        const int row = m0 + r;

        // a_n: numpy pairwise f32 sum of z^2 (AVX512 NPYV order)
        float blk[2];
#pragma unroll
        for (int bb = 0; bb < 2; ++bb) {
            float tarr[8];
#pragma unroll
            for (int t8 = 0; t8 < 8; ++t8) {
                float zz = zs[r * C_DIM + ((bb * 128 + t8 * 16 + tx) ^ zsw)];
                tarr[t8] = zz * zz;
            }
            float p01 = tarr[0] + tarr[1];
            float p23 = tarr[2] + tarr[3];
            float p45 = tarr[4] + tarr[5];
            float p67 = tarr[6] + tarr[7];
            float W = (p01 + p23) + (p45 + p67);
            W += __shfl_xor(W, 8, 64);
            W += __shfl_xor(W, 4, 64);
            W += __shfl_xor(W, 2, 64);
            W += __shfl_xor(W, 1, 64);
            blk[bb] = W;
        }
        const float af = blk[0] + blk[1];

        float bestd = 3.4e38f; int besti = 0x7fffffff;
        for (int c = 0; c < 8; ++c) {
            const int ci = cand[row * 8 + c];
            const float* wp = w + (size_t)ci * C_DIM;
            double ss = 0, qq = 0;
            const int cb = tx * 16;
#pragma unroll
            for (int cc = 0; cc < 16; cc += 4) {
                const int col = cb + cc;
                float4 zv = *(const float4*)&zs[r * C_DIM + (col ^ zsw)];
                float4 wa = *(const float4*)(wp + col);
                ss += (double)zv.x * wa.x + (double)zv.y * wa.y + (double)zv.z * wa.z + (double)zv.w * wa.w;
                qq += (double)wa.x * wa.x + (double)wa.y * wa.y + (double)wa.z * wa.z + (double)wa.w * wa.w;
            }
#pragma unroll
            for (int st = 1; st <= 8; st <<= 1) {
                ss += __shfl_xor(ss, st, 64);
                qq += __shfl_xor(qq, st, 64);
            }
            const float d = (af + (float)qq) - (float)(2.0 * ss);
            if (d < bestd || (d == bestd && ci < besti)) { bestd = d; besti = ci; }
        }
        if (tx == 0) idx[row] = besti;
    }
}

// ===================== K3: gather/STE + loss + embed_sum + counts + idx_out =====
__global__ __launch_bounds__(256) void k_gather(const float* __restrict__ z,
                                                const float* __restrict__ w,
                                                const int* __restrict__ idx,
                                                float* __restrict__ zq,
                                                float* __restrict__ oidx,
                                                float* __restrict__ esum,
                                                float* __restrict__ cnt,
                                                float* __restrict__ lpart)
{
    const int bid = blockIdx.x;
    const int b   = bid >> 8;
    const int c   = bid & 255;
    const int tid = threadIdx.x;
    const int hw4 = tid * 4;
    const size_t zoff = (size_t)b * (C_DIM * HWSZ) + (size_t)c * HWSZ + hw4;

    float4 zv = *(const float4*)(z + zoff);
    const int nb = b * HWSZ + hw4;
    int4 iv = *(const int4*)(idx + nb);

    float4 wq;
    wq.x = w[(size_t)iv.x * C_DIM + c];
    wq.y = w[(size_t)iv.y * C_DIM + c];
    wq.z = w[(size_t)iv.z * C_DIM + c];
    wq.w = w[(size_t)iv.w * C_DIM + c];
    *(float4*)(zq + zoff) = wq;

    float dx = wq.x - zv.x, dy = wq.y - zv.y, dz = wq.z - zv.z, dw = wq.w - zv.w;
    float ls = dx * dx + dy * dy + dz * dz + dw * dw;

    atomicAdd(esum + (size_t)iv.x * C_DIM + c, zv.x);
    atomicAdd(esum + (size_t)iv.y * C_DIM + c, zv.y);
    atomicAdd(esum + (size_t)iv.z * C_DIM + c, zv.z);
    atomicAdd(esum + (size_t)iv.w * C_DIM + c, zv.w);

    if (c == 0) {   // idx as floats; odd offset -> scalar stores
        oidx[nb + 0] = (float)iv.x;
        oidx[nb + 1] = (float)iv.y;
        oidx[nb + 2] = (float)iv.z;
        oidx[nb + 3] = (float)iv.w;
    }
    if (c == 1) {
        atomicAdd(cnt + iv.x, 1.f); atomicAdd(cnt + iv.y, 1.f);
        atomicAdd(cnt + iv.z, 1.f); atomicAdd(cnt + iv.w, 1.f);
    }

#pragma unroll
    for (int d = 1; d < 64; d <<= 1) ls += __shfl_xor(ls, d, 64);
    __shared__ float red[4];
    if ((tid & 63) == 0) red[tid >> 6] = ls;
    __syncthreads();
    if (tid == 0) lpart[bid] = red[0] + red[1] + red[2] + red[3];
}

// ===================== K4a: n_total, perplexity, loss =====================
__global__ __launch_bounds__(256) void k_stats(const float* __restrict__ cnt,
                                               const float* __restrict__ cs,
                                               const float* __restrict__ lpart,
                                               float* __restrict__ ntot,
                                               float* __restrict__ out_loss,
                                               float* __restrict__ out_perp)
{
    const int tid = threadIdx.x;
    float sn = 0.f, se = 0.f, sl = 0.f;
    for (int k = tid; k < K_CODES; k += 256) {
        float cn = cnt[k];
        sn += 0.99f * cs[k] + 0.01f * cn;
        float p = cn * (1.f / (float)N_TOTAL);
        se += p * logf(p + 1e-10f);
    }
    for (int i = tid; i < 4096; i += 256) sl += lpart[i];
#pragma unroll
    for (int d = 1; d < 64; d <<= 1) {
        sn += __shfl_xor(sn, d, 64);
        se += __shfl_xor(se, d, 64);
        sl += __shfl_xor(sl, d, 64);
    }
    __shared__ float r[12];
    if ((tid & 63) == 0) { int wv = tid >> 6; r[wv] = sn; r[4 + wv] = se; r[8 + wv] = sl; }
    __syncthreads();
    if (tid == 0) {
        float n = r[0] + r[1] + r[2] + r[3];
        float e = r[4] + r[5] + r[6] + r[7];
        float l = r[8] + r[9] + r[10] + r[11];
        *ntot = n;
        *out_loss = 0.25f * l * (1.f / 4194304.f);
        *out_perp = expf(-e);
    }
}

// ===================== K4b: EMA update + normalized weight =====================
// esum aliases o_ea (scratch-in-output); per-element read-then-overwrite is safe.
__global__ __launch_bounds__(256) void k_update(const float* __restrict__ cs,
                                                const float* __restrict__ cnt,
                                                const float* __restrict__ ea,
                                                const float* __restrict__ esum,
                                                const float* __restrict__ ntot,
                                                float* __restrict__ o_w,
                                                float* __restrict__ o_cs,
                                                float* __restrict__ o_ea)
{
    const int k = blockIdx.x;
    const int c = threadIdx.x;
    float ncs = 0.99f * cs[k] + 0.01f * cnt[k];
    float n = *ntot;
    float sm = (ncs + 1e-5f) / (n + (float)K_CODES * 1e-5f) * n;
    if (c == 0) o_cs[k] = ncs;
    size_t o = (size_t)k * C_DIM + c;
    float v = 0.99f * ea[o] + 0.01f * esum[o];
    o_ea[o] = v;
    o_w[o]  = v / sm;
}

// ===================== launch =====================
extern "C" void kernel_launch(void* const* d_in, const int* in_sizes, int n_in,
                              void* d_out, int out_size, void* d_ws, size_t ws_size,
                              hipStream_t stream)
{
    const float* z  = (const float*)d_in[0];
    const float* w  = (const float*)d_in[1];
    const float* cs = (const float*)d_in[2];
    const float* ea = (const float*)d_in[3];
    float* out = (float*)d_out;
    float* ws  = (float*)d_ws;

    float* wn    = ws + WS_WN;
    int*   idx   = (int*)(ws + WS_IDX);
    float* cnt   = ws + WS_CNT;
    float* lpart = ws + WS_LPART;
    float* ntot  = ws + WS_NTOT;
    int*   cand  = (int*)(ws + WS_CAND);
    float* esum  = out + O_EA;   // scratch-in-output: zeroed, accumulated, overwritten

    // f16 hi/lo scratch lives in out regions that are overwritten at the end:
    // zhi/zlo in O_ZQ (16.8 MB, exact fit); whi/wlo in O_W (+2 floats for 16B align;
    // 2-float spill into O_CS is overwritten by k_update afterwards).
    f16* zhi = (f16*)(out + O_ZQ);
    f16* zlo = zhi + (size_t)N_TOTAL * C_DIM;
    f16* whi = (f16*)(out + O_W + 2);
    f16* wlo = whi + (size_t)K_CODES * C_DIM;

    hipMemsetAsync(cnt, 0, K_CODES * sizeof(float), stream);
    hipMemsetAsync(esum, 0, (size_t)K_CODES * C_DIM * sizeof(float), stream);

    k_prepz <<<N_TOTAL / 32, 256, 0, stream>>>(z, zhi, zlo);
    k_prepw <<<K_CODES * C_DIM / (256 * 8), 256, 0, stream>>>(w, whi, wlo);
    k_wnorm <<<K_CODES / 4, 256, 0, stream>>>(w, wn);
    k_select<<<dim3(N_TOTAL / 256, 4), 512, 0, stream>>>(zhi, zlo, whi, wlo, wn, cand);
    k_rerank<<<N_TOTAL / 32, 256, 0, stream>>>(z, w, cand, idx);
    k_gather<<<16 * 256, 256, 0, stream>>>(z, w, idx, out + O_ZQ, out + O_IDX,
                                           esum, cnt, lpart);
    k_stats <<<1, 256, 0, stream>>>(cnt, cs, lpart, ntot, out + O_LOSS, out + O_PERP);
    k_update<<<K_CODES, 256, 0, stream>>>(cs, cnt, ea, esum, ntot,
                                          out + O_W, out + O_CS, out + O_EA);
}